// Round 3
// baseline (1491.440 us; speedup 1.0000x reference)
//
#include <hip/hip_runtime.h>
#include <hip/hip_bf16.h>

// Problem constants (B=16, F=8, NP=196, D=768, H=12)
#define BATCH 16
#define NFRAME 8
#define NPF 196          // tokens per frame
#define DIM 768
#define NHEAD 12
#define DHEAD 64
#define NTOK 1569        // 1 + 8*196
#define MROWS (BATCH * NTOK)   // 25104
#define D3 (3 * DIM)           // 2304
#define QKCOLS 1536      // Q+K columns kept in ws (bf16)
#define NKEY 197         // CLS + frame keys
#define NKP 224          // padded keys (7*32)
#define VST 232          // LDS row stride (16B-aligned, decent banking)
#define PST 232

typedef __attribute__((ext_vector_type(8))) short short8;
typedef __attribute__((ext_vector_type(4))) float floatx4;

#define MFMA16(A, B, C) __builtin_amdgcn_mfma_f32_16x16x32_bf16((A), (B), (C), 0, 0, 0)

__device__ __forceinline__ float bf2f(short s) {
    union { unsigned u; float f; } x;
    x.u = ((unsigned)(unsigned short)s) << 16;
    return x.f;
}
__device__ __forceinline__ short f2bf(float f) {
    union { float f; unsigned u; } x;
    x.f = f;
    unsigned r = x.u + 0x7fffu + ((x.u >> 16) & 1u);  // RNE
    return (short)(r >> 16);
}

// ---------------------------------------------------------------------------
// Fallback when ws_size is too small: zero d_out (clean diagnostic signal)
// ---------------------------------------------------------------------------
__global__ __launch_bounds__(256) void zero_out_k(float* __restrict__ out, int n) {
    int i = blockIdx.x * 256 + threadIdx.x;
    if (i < n) out[i] = 0.f;
}

// ---------------------------------------------------------------------------
// Weight transpose + fp32->bf16: in fp32 (R x C) -> out bf16 (C x R)
// ---------------------------------------------------------------------------
__global__ __launch_bounds__(256) void transpose_cvt_k(const float* __restrict__ in,
                                                       short* __restrict__ out,
                                                       int R, int C) {
    __shared__ float tile[32][33];
    int tx = threadIdx.x & 31, ty = threadIdx.x >> 5;  // ty 0..7
    int r0 = blockIdx.y * 32, c0 = blockIdx.x * 32;
    for (int i = 0; i < 4; ++i) {
        int r = ty + i * 8;
        tile[r][tx] = in[(size_t)(r0 + r) * C + c0 + tx];
    }
    __syncthreads();
    for (int i = 0; i < 4; ++i) {
        int c = ty + i * 8;
        out[(size_t)(c0 + c) * R + r0 + tx] = f2bf(tile[tx][c]);
    }
}

// ---------------------------------------------------------------------------
// GEMM: C[M x Nc] = A[M x K] * BT[Nc x K]^T (+ bias), fp32 acc.
// A is fp32 (converted to bf16 in-register) or bf16 per AF32.
// Output fp32 or bf16 per OF32. Split store: cols < nsplit -> C0, else C1.
// block = 256 threads = 4 waves; block tile 64x64; wave tile 32x32.
// ---------------------------------------------------------------------------
template <bool AF32, bool OF32>
__global__ __launch_bounds__(256) void gemm_bt(const void* __restrict__ Av, int lda,
                                               const short* __restrict__ BT,
                                               const float* __restrict__ bias,
                                               void* __restrict__ C0v, int ldc0,
                                               void* __restrict__ C1v, int ldc1,
                                               int nsplit,
                                               int M, int Nc, int K) {
    int lane = threadIdx.x & 63;
    int wid = threadIdx.x >> 6;
    int l16 = lane & 15, quad = lane >> 4;
    int m0 = blockIdx.x * 64 + (wid & 1) * 32;
    int n0 = blockIdx.y * 64 + (wid >> 1) * 32;

    floatx4 acc[2][2];
    for (int mt = 0; mt < 2; ++mt)
        for (int nt = 0; nt < 2; ++nt)
            acc[mt][nt] = (floatx4){0.f, 0.f, 0.f, 0.f};

    int arow[2];
    for (int mt = 0; mt < 2; ++mt) {
        int r = m0 + mt * 16 + l16;
        arow[mt] = (r < M) ? r : (M - 1);
    }
    int brow[2];
    for (int nt = 0; nt < 2; ++nt) brow[nt] = n0 + nt * 16 + l16;

    for (int k0 = 0; k0 < K; k0 += 32) {
        short8 a[2], b[2];
        for (int mt = 0; mt < 2; ++mt) {
            if (AF32) {
                const float* Af = (const float*)Av + (size_t)arow[mt] * lda + k0 + quad * 8;
                float4 u0 = *(const float4*)(Af);
                float4 u1 = *(const float4*)(Af + 4);
                short8 t;
                t[0] = f2bf(u0.x); t[1] = f2bf(u0.y); t[2] = f2bf(u0.z); t[3] = f2bf(u0.w);
                t[4] = f2bf(u1.x); t[5] = f2bf(u1.y); t[6] = f2bf(u1.z); t[7] = f2bf(u1.w);
                a[mt] = t;
            } else {
                a[mt] = *(const short8*)((const short*)Av + (size_t)arow[mt] * lda + k0 + quad * 8);
            }
        }
        for (int nt = 0; nt < 2; ++nt)
            b[nt] = *(const short8*)(BT + (size_t)brow[nt] * K + k0 + quad * 8);
        for (int mt = 0; mt < 2; ++mt)
            for (int nt = 0; nt < 2; ++nt)
                acc[mt][nt] = MFMA16(a[mt], b[nt], acc[mt][nt]);
    }

    for (int mt = 0; mt < 2; ++mt)
        for (int nt = 0; nt < 2; ++nt) {
            int col0 = n0 + nt * 16;               // 16-aligned; nsplit mult of 16
            void* dst;
            int ldc, cbase;
            if (col0 < nsplit) { dst = C0v; ldc = ldc0; cbase = col0; }
            else               { dst = C1v; ldc = ldc1; cbase = col0 - nsplit; }
            for (int r = 0; r < 4; ++r) {
                int row = m0 + mt * 16 + quad * 4 + r;
                if (row < M) {
                    float v = acc[mt][nt][r];
                    if (bias) v += bias[col0 + l16];
                    if (OF32)
                        ((float*)dst)[(size_t)row * ldc + cbase + l16] = v;
                    else
                        ((short*)dst)[(size_t)row * ldc + cbase + l16] = f2bf(v);
                }
            }
        }
}

// ---------------------------------------------------------------------------
// Frame attention: one block (4 waves) per (b, h, f). All bf16 I/O.
// Q at qk[row*1536 + h*64], K at qk[row*1536 + 768 + h*64], V at v[row*768+h*64].
// Output O overwrites the Q slot of the same rows/cols (Q read before write;
// q-tiles partition rows; K region never written).
// ---------------------------------------------------------------------------
__global__ __launch_bounds__(256) void frame_attn(short* __restrict__ qk,
                                                  const short* __restrict__ vsrc) {
    __shared__ __align__(16) short VT[DHEAD * VST];      // 29696 B
    __shared__ __align__(16) short P[4][16 * PST];       // 29696 B

    int blk = blockIdx.x;
    int f = blk & 7;
    int h = (blk >> 3) % NHEAD;
    int b = blk / (NHEAD * NFRAME);
    int lane = threadIdx.x & 63, wid = threadIdx.x >> 6;
    int l16 = lane & 15, quad = lane >> 4;
    const size_t basetok = (size_t)b * NTOK;
    const int hc = h * DHEAD;

    // Stage V transposed: VT[dd][j] = V[key j][dd]; pad j>=197 with 0
    for (int e = threadIdx.x; e < NKP * DHEAD; e += 256) {
        int j = e >> 6, dd = e & 63;
        short v = 0;
        if (j < NKEY) {
            int tok = (j == 0) ? 0 : (f * NPF + j);
            v = vsrc[(basetok + tok) * DIM + hc + dd];
        }
        VT[dd * VST + j] = v;
    }
    __syncthreads();

    const float scale = 0.125f;  // d^-0.5, d=64

    for (int it = 0; it < 4; ++it) {
        int qt = wid + it * 4;            // q-tile index, 13 valid tiles (196 rows)
        bool active = qt < 13;
        float inv_sum[4] = {0.f, 0.f, 0.f, 0.f};

        if (active) {
            floatx4 S[14];
            for (int nt = 0; nt < 14; ++nt) S[nt] = (floatx4){0.f, 0.f, 0.f, 0.f};

            int qm = qt * 16 + l16;
            if (qm > 195) qm = 195;       // clamp pad rows (results discarded)
            int qtok = 1 + f * NPF + qm;
            const short* qrow = qk + (basetok + qtok) * QKCOLS + hc;
            short8 afrag[2];
            afrag[0] = *(const short8*)(qrow + quad * 8);
            afrag[1] = *(const short8*)(qrow + 32 + quad * 8);

            for (int nt = 0; nt < 14; ++nt) {
                int key = nt * 16 + l16;
                int ktok = (key == 0) ? 0 : ((key <= 196) ? (f * NPF + key) : 0);
                const short* krow = qk + (basetok + ktok) * QKCOLS + DIM + hc;
                short8 b0 = *(const short8*)(krow + quad * 8);
                short8 b1 = *(const short8*)(krow + 32 + quad * 8);
                S[nt] = MFMA16(afrag[0], b0, S[nt]);
                S[nt] = MFMA16(afrag[1], b1, S[nt]);
            }

            // scale + mask padded key columns
            for (int nt = 0; nt < 14; ++nt) {
                int key = nt * 16 + l16;
                float mask = (key < NKEY) ? 0.f : -1e30f;
                for (int r = 0; r < 4; ++r) S[nt][r] = S[nt][r] * scale + mask;
            }

            // softmax: row = quad*4+r, spread over the quad's 16 lanes
            for (int r = 0; r < 4; ++r) {
                float m = -1e30f;
                for (int nt = 0; nt < 14; ++nt) m = fmaxf(m, S[nt][r]);
                for (int off = 1; off < 16; off <<= 1) m = fmaxf(m, __shfl_xor(m, off, 64));
                float s = 0.f;
                for (int nt = 0; nt < 14; ++nt) {
                    float e = __expf(S[nt][r] - m);
                    S[nt][r] = e;
                    s += e;
                }
                for (int off = 1; off < 16; off <<= 1) s += __shfl_xor(s, off, 64);
                inv_sum[r] = 1.0f / s;
            }

            // write P (unnormalized) to per-wave LDS in row-major (A-layout source)
            for (int nt = 0; nt < 14; ++nt)
                for (int r = 0; r < 4; ++r)
                    P[wid][(quad * 4 + r) * PST + nt * 16 + l16] = f2bf(S[nt][r]);
        }
        __syncthreads();

        if (active) {
            floatx4 O[4];
            for (int dt = 0; dt < 4; ++dt) O[dt] = (floatx4){0.f, 0.f, 0.f, 0.f};
            for (int ks = 0; ks < 7; ++ks) {
                short8 af = *(const short8*)&P[wid][l16 * PST + ks * 32 + quad * 8];
                for (int dt = 0; dt < 4; ++dt) {
                    short8 bf_ = *(const short8*)&VT[(dt * 16 + l16) * VST + ks * 32 + quad * 8];
                    O[dt] = MFMA16(af, bf_, O[dt]);
                }
            }
            for (int dt = 0; dt < 4; ++dt)
                for (int r = 0; r < 4; ++r) {
                    int m = qt * 16 + quad * 4 + r;
                    if (m < NPF) {
                        int tok = 1 + f * NPF + m;
                        qk[(basetok + tok) * QKCOLS + hc + dt * 16 + l16] =
                            f2bf(O[dt][r] * inv_sum[r]);
                    }
                }
        }
        __syncthreads();
    }
}

// ---------------------------------------------------------------------------
// CLS attention: one block per (b, h); CLS query attends to all 1569 keys.
// Reads Q token 0 / K from qk (bf16), V from vsrc (bf16); writes O into Q slot.
// ---------------------------------------------------------------------------
__global__ __launch_bounds__(256) void cls_attn(short* __restrict__ qk,
                                                const short* __restrict__ vsrc) {
    __shared__ float qs[DHEAD];
    __shared__ float sexp[NTOK];
    __shared__ float red[8];
    __shared__ float partial[4][DHEAD];

    int h = blockIdx.x % NHEAD, b = blockIdx.x / NHEAD;
    const size_t basetok = (size_t)b * NTOK;
    const int hc = h * DHEAD;
    int tid = threadIdx.x;

    if (tid < DHEAD) qs[tid] = bf2f(qk[basetok * QKCOLS + hc + tid]) * 0.125f;
    __syncthreads();

    float lmax = -1e30f;
    for (int j = tid; j < NTOK; j += 256) {
        const short* krow = qk + (basetok + j) * QKCOLS + DIM + hc;
        float s = 0.f;
        for (int dd = 0; dd < DHEAD; ++dd) s += qs[dd] * bf2f(krow[dd]);
        sexp[j] = s;
        lmax = fmaxf(lmax, s);
    }
    for (int off = 1; off < 64; off <<= 1) lmax = fmaxf(lmax, __shfl_xor(lmax, off, 64));
    if ((tid & 63) == 0) red[tid >> 6] = lmax;
    __syncthreads();
    float mx = fmaxf(fmaxf(red[0], red[1]), fmaxf(red[2], red[3]));

    float lsum = 0.f;
    for (int j = tid; j < NTOK; j += 256) {
        float e = __expf(sexp[j] - mx);
        sexp[j] = e;
        lsum += e;
    }
    for (int off = 1; off < 64; off <<= 1) lsum += __shfl_xor(lsum, off, 64);
    if ((tid & 63) == 0) red[4 + (tid >> 6)] = lsum;
    __syncthreads();
    float sum = red[4] + red[5] + red[6] + red[7];

    int dd = tid & 63, strip = tid >> 6;
    float acc = 0.f;
    for (int j = strip; j < NTOK; j += 4)
        acc += sexp[j] * bf2f(vsrc[(basetok + j) * DIM + hc + dd]);
    partial[strip][dd] = acc;
    __syncthreads();

    if (tid < DHEAD) {
        float o = (partial[0][tid] + partial[1][tid] + partial[2][tid] + partial[3][tid]) / sum;
        qk[basetok * QKCOLS + hc + tid] = f2bf(o);
    }
}

// ---------------------------------------------------------------------------
extern "C" void kernel_launch(void* const* d_in, const int* in_sizes, int n_in,
                              void* d_out, int out_size, void* d_ws, size_t ws_size,
                              hipStream_t stream) {
    const float* x      = (const float*)d_in[0];   // (B, N, D) fp32
    const float* w_qkv  = (const float*)d_in[1];   // (D, 3D) fp32
    const float* w_proj = (const float*)d_in[2];   // (D, D) fp32
    const float* b_proj = (const float*)d_in[3];   // (D,) fp32
    float* out = (float*)d_out;                    // fp32 output (77 MB)
    short* vbuf = (short*)d_out;                   // V as bf16 in d_out scratch (38.6 MB)

    // ws layout: qk bf16 (MROWS x 1536) | wqkvT bf16 (2304x768) | wprojT bf16 (768x768)
    const size_t QK_EL     = (size_t)MROWS * QKCOLS;         // 38,559,744
    const size_t WQKVT_EL  = (size_t)D3 * DIM;               //  1,769,472
    const size_t WPROJT_EL = (size_t)DIM * DIM;              //    589,824
    const size_t WS_NEEDED = (QK_EL + WQKVT_EL + WPROJT_EL) * sizeof(short); // ~82 MB

    if (ws_size < WS_NEEDED) {
        zero_out_k<<<(out_size + 255) / 256, 256, 0, stream>>>(out, out_size);
        return;
    }

    short* qk     = (short*)d_ws;
    short* wqkvT  = qk + QK_EL;
    short* wprojT = wqkvT + WQKVT_EL;

    transpose_cvt_k<<<dim3(D3 / 32, DIM / 32), 256, 0, stream>>>(w_qkv, wqkvT, DIM, D3);
    transpose_cvt_k<<<dim3(DIM / 32, DIM / 32), 256, 0, stream>>>(w_proj, wprojT, DIM, DIM);

    // qkv = x @ w_qkv ; cols 0..1535 (Q,K) -> qk (bf16), cols 1536.. (V) -> vbuf (bf16)
    gemm_bt<true, false><<<dim3((MROWS + 63) / 64, D3 / 64), 256, 0, stream>>>(
        x, DIM, wqkvT, nullptr, qk, QKCOLS, vbuf, DIM, QKCOLS, MROWS, D3, DIM);

    frame_attn<<<BATCH * NHEAD * NFRAME, 256, 0, stream>>>(qk, vbuf);
    cls_attn<<<BATCH * NHEAD, 256, 0, stream>>>(qk, vbuf);

    // out = attnout @ w_proj + b_proj  (attnout = qk's Q region, lda=1536; fp32 out)
    gemm_bt<false, true><<<dim3((MROWS + 63) / 64, DIM / 64), 256, 0, stream>>>(
        qk, QKCOLS, wprojT, b_proj, out, DIM, nullptr, 0, D3 /*no split*/,
        MROWS, DIM, DIM);
}

// Round 4
// 627.125 us; speedup vs baseline: 2.3782x; 2.3782x over previous
//
#include <hip/hip_runtime.h>
#include <hip/hip_bf16.h>

// Problem constants (B=16, F=8, NP=196, D=768, H=12)
#define BATCH 16
#define NFRAME 8
#define NPF 196          // tokens per frame
#define DIM 768
#define NHEAD 12
#define DHEAD 64
#define NTOK 1569        // 1 + 8*196
#define MROWS (BATCH * NTOK)   // 25104
#define D3 (3 * DIM)           // 2304
#define QKCOLS 1536      // Q+K columns kept in ws (bf16)
#define NKEY 197         // CLS + frame keys
#define NKP 224          // padded keys (7*32)
#define VST 232          // LDS row stride (16B-aligned, decent banking)
#define PST 232

typedef __attribute__((ext_vector_type(8))) short short8;
typedef __attribute__((ext_vector_type(4))) float floatx4;

#define MFMA16(A, B, C) __builtin_amdgcn_mfma_f32_16x16x32_bf16((A), (B), (C), 0, 0, 0)

__device__ __forceinline__ float bf2f(short s) {
    union { unsigned u; float f; } x;
    x.u = ((unsigned)(unsigned short)s) << 16;
    return x.f;
}
__device__ __forceinline__ short f2bf(float f) {
    union { float f; unsigned u; } x;
    x.f = f;
    unsigned r = x.u + 0x7fffu + ((x.u >> 16) & 1u);  // RNE
    return (short)(r >> 16);
}

// async global(bf16)->LDS, 16 bytes per lane
__device__ __forceinline__ void gld_lds16(const short* g, short* l) {
    __builtin_amdgcn_global_load_lds(
        (const __attribute__((address_space(1))) void*)g,
        (__attribute__((address_space(3))) void*)l, 16, 0, 0);
}

// ---------------------------------------------------------------------------
// Fallback when ws_size is too small: zero d_out (clean diagnostic signal)
// ---------------------------------------------------------------------------
__global__ __launch_bounds__(256) void zero_out_k(float* __restrict__ out, int n) {
    int i = blockIdx.x * 256 + threadIdx.x;
    if (i < n) out[i] = 0.f;
}

// ---------------------------------------------------------------------------
// fp32 -> bf16 convert, 8 elements/thread
// ---------------------------------------------------------------------------
__global__ __launch_bounds__(256) void cvt_bf16_k(const float* __restrict__ in,
                                                  short* __restrict__ out, int n8) {
    int i = blockIdx.x * 256 + threadIdx.x;
    if (i < n8) {
        const float4* p = (const float4*)(in + (size_t)i * 8);
        float4 u0 = p[0], u1 = p[1];
        short8 t;
        t[0] = f2bf(u0.x); t[1] = f2bf(u0.y); t[2] = f2bf(u0.z); t[3] = f2bf(u0.w);
        t[4] = f2bf(u1.x); t[5] = f2bf(u1.y); t[6] = f2bf(u1.z); t[7] = f2bf(u1.w);
        *(short8*)(out + (size_t)i * 8) = t;
    }
}

// ---------------------------------------------------------------------------
// Weight transpose + fp32->bf16: in fp32 (R x C) -> out bf16 (C x R)
// ---------------------------------------------------------------------------
__global__ __launch_bounds__(256) void transpose_cvt_k(const float* __restrict__ in,
                                                       short* __restrict__ out,
                                                       int R, int C) {
    __shared__ float tile[32][33];
    int tx = threadIdx.x & 31, ty = threadIdx.x >> 5;  // ty 0..7
    int r0 = blockIdx.y * 32, c0 = blockIdx.x * 32;
    for (int i = 0; i < 4; ++i) {
        int r = ty + i * 8;
        tile[r][tx] = in[(size_t)(r0 + r) * C + c0 + tx];
    }
    __syncthreads();
    for (int i = 0; i < 4; ++i) {
        int c = ty + i * 8;
        out[(size_t)(c0 + c) * R + r0 + tx] = f2bf(tile[tx][c]);
    }
}

// ---------------------------------------------------------------------------
// LDS-tiled GEMM (m97 structure): C[M x Nc] = A[M x K] * BT[Nc x K]^T (+bias)
// A bf16 (lda elems), BT bf16 (K-major, ld = K). 128x128 block tile, BK=32,
// 4 waves x (4x4 of 16x16x32 MFMA), global_load_lds width-16 staging,
// 2-barrier K-loop. Split store: global col < nsplit -> C0 else C1.
// grid = (Nc/128, ceil(M/128))
// ---------------------------------------------------------------------------
template <bool OF32>
__global__ __launch_bounds__(256) void gemm_lds(const short* __restrict__ A, int lda,
                                                const short* __restrict__ BT,
                                                const float* __restrict__ bias,
                                                void* __restrict__ C0v, int ldc0,
                                                void* __restrict__ C1v, int ldc1,
                                                int nsplit, int M, int K) {
    __shared__ __align__(16) short As[128 * 32];
    __shared__ __align__(16) short Bs[128 * 32];

    int tid = threadIdx.x;
    int lane = tid & 63, wid = tid >> 6;
    int l16 = lane & 15, quad = lane >> 4;
    int n0 = blockIdx.x * 128, m0 = blockIdx.y * 128;
    int wm = (wid & 1) * 64, wn = (wid >> 1) * 64;

    // staging: chunk c (0..1): linear id = c*256+tid; row = id>>2, kcol = (id&3)*8
    int id0 = tid, id1 = tid + 256;
    int ar0 = id0 >> 2, ak0 = (id0 & 3) * 8;
    int ar1 = id1 >> 2, ak1 = (id1 & 3) * 8;
    int ga0 = m0 + ar0; if (ga0 >= M) ga0 = M - 1;
    int ga1 = m0 + ar1; if (ga1 >= M) ga1 = M - 1;
    const short* Ap0 = A + (size_t)ga0 * lda + ak0;
    const short* Ap1 = A + (size_t)ga1 * lda + ak1;
    const short* Bp0 = BT + (size_t)(n0 + ar0) * K + ak0;
    const short* Bp1 = BT + (size_t)(n0 + ar1) * K + ak1;

    floatx4 acc[4][4];
    for (int mt = 0; mt < 4; ++mt)
        for (int nt = 0; nt < 4; ++nt)
            acc[mt][nt] = (floatx4){0.f, 0.f, 0.f, 0.f};

    for (int k0 = 0; k0 < K; k0 += 32) {
        if (k0) __syncthreads();                 // prev-iter LDS reads done
        gld_lds16(Ap0 + k0, &As[id0 * 8]);
        gld_lds16(Ap1 + k0, &As[id1 * 8]);
        gld_lds16(Bp0 + k0, &Bs[id0 * 8]);
        gld_lds16(Bp1 + k0, &Bs[id1 * 8]);
        __syncthreads();                         // vmcnt drain + barrier

        short8 a[4], b[4];
        for (int mt = 0; mt < 4; ++mt)
            a[mt] = *(const short8*)&As[(wm + mt * 16 + l16) * 32 + quad * 8];
        for (int nt = 0; nt < 4; ++nt)
            b[nt] = *(const short8*)&Bs[(wn + nt * 16 + l16) * 32 + quad * 8];
        for (int mt = 0; mt < 4; ++mt)
            for (int nt = 0; nt < 4; ++nt)
                acc[mt][nt] = MFMA16(a[mt], b[nt], acc[mt][nt]);
    }

    for (int mt = 0; mt < 4; ++mt)
        for (int nt = 0; nt < 4; ++nt) {
            int col0 = n0 + wn + nt * 16;        // 16-aligned; nsplit mult of 16
            void* dst;
            int ldc, cbase;
            if (col0 < nsplit) { dst = C0v; ldc = ldc0; cbase = col0; }
            else               { dst = C1v; ldc = ldc1; cbase = col0 - nsplit; }
            float bv = bias ? bias[col0 + l16] : 0.f;
            for (int r = 0; r < 4; ++r) {
                int row = m0 + wm + mt * 16 + quad * 4 + r;
                if (row < M) {
                    float v = acc[mt][nt][r] + bv;
                    if (OF32)
                        ((float*)dst)[(size_t)row * ldc + cbase + l16] = v;
                    else
                        ((short*)dst)[(size_t)row * ldc + cbase + l16] = f2bf(v);
                }
            }
        }
}

// ---------------------------------------------------------------------------
// Frame attention: one block (4 waves) per (b, h, f). All bf16 I/O.
// Q at qk[row*1536 + h*64], K at qk[row*1536 + 768 + h*64], V at v[row*768+h*64].
// Output O overwrites the Q slot of the same rows/cols.
// ---------------------------------------------------------------------------
__global__ __launch_bounds__(256) void frame_attn(short* __restrict__ qk,
                                                  const short* __restrict__ vsrc) {
    __shared__ __align__(16) short VT[DHEAD * VST];      // 29696 B
    __shared__ __align__(16) short P[4][16 * PST];       // 29696 B

    int blk = blockIdx.x;
    int f = blk & 7;
    int h = (blk >> 3) % NHEAD;
    int b = blk / (NHEAD * NFRAME);
    int lane = threadIdx.x & 63, wid = threadIdx.x >> 6;
    int l16 = lane & 15, quad = lane >> 4;
    const size_t basetok = (size_t)b * NTOK;
    const int hc = h * DHEAD;

    for (int e = threadIdx.x; e < NKP * DHEAD; e += 256) {
        int j = e >> 6, dd = e & 63;
        short v = 0;
        if (j < NKEY) {
            int tok = (j == 0) ? 0 : (f * NPF + j);
            v = vsrc[(basetok + tok) * DIM + hc + dd];
        }
        VT[dd * VST + j] = v;
    }
    __syncthreads();

    const float scale = 0.125f;  // d^-0.5, d=64

    for (int it = 0; it < 4; ++it) {
        int qt = wid + it * 4;            // q-tile index, 13 valid tiles (196 rows)
        bool active = qt < 13;
        float inv_sum[4] = {0.f, 0.f, 0.f, 0.f};

        if (active) {
            floatx4 S[14];
            for (int nt = 0; nt < 14; ++nt) S[nt] = (floatx4){0.f, 0.f, 0.f, 0.f};

            int qm = qt * 16 + l16;
            if (qm > 195) qm = 195;       // clamp pad rows (results discarded)
            int qtok = 1 + f * NPF + qm;
            const short* qrow = qk + (basetok + qtok) * QKCOLS + hc;
            short8 afrag[2];
            afrag[0] = *(const short8*)(qrow + quad * 8);
            afrag[1] = *(const short8*)(qrow + 32 + quad * 8);

            for (int nt = 0; nt < 14; ++nt) {
                int key = nt * 16 + l16;
                int ktok = (key == 0) ? 0 : ((key <= 196) ? (f * NPF + key) : 0);
                const short* krow = qk + (basetok + ktok) * QKCOLS + DIM + hc;
                short8 b0 = *(const short8*)(krow + quad * 8);
                short8 b1 = *(const short8*)(krow + 32 + quad * 8);
                S[nt] = MFMA16(afrag[0], b0, S[nt]);
                S[nt] = MFMA16(afrag[1], b1, S[nt]);
            }

            for (int nt = 0; nt < 14; ++nt) {
                int key = nt * 16 + l16;
                float mask = (key < NKEY) ? 0.f : -1e30f;
                for (int r = 0; r < 4; ++r) S[nt][r] = S[nt][r] * scale + mask;
            }

            for (int r = 0; r < 4; ++r) {
                float m = -1e30f;
                for (int nt = 0; nt < 14; ++nt) m = fmaxf(m, S[nt][r]);
                for (int off = 1; off < 16; off <<= 1) m = fmaxf(m, __shfl_xor(m, off, 64));
                float s = 0.f;
                for (int nt = 0; nt < 14; ++nt) {
                    float e = __expf(S[nt][r] - m);
                    S[nt][r] = e;
                    s += e;
                }
                for (int off = 1; off < 16; off <<= 1) s += __shfl_xor(s, off, 64);
                inv_sum[r] = 1.0f / s;
            }

            for (int nt = 0; nt < 14; ++nt)
                for (int r = 0; r < 4; ++r)
                    P[wid][(quad * 4 + r) * PST + nt * 16 + l16] = f2bf(S[nt][r]);
        }
        __syncthreads();

        if (active) {
            floatx4 O[4];
            for (int dt = 0; dt < 4; ++dt) O[dt] = (floatx4){0.f, 0.f, 0.f, 0.f};
            for (int ks = 0; ks < 7; ++ks) {
                short8 af = *(const short8*)&P[wid][l16 * PST + ks * 32 + quad * 8];
                for (int dt = 0; dt < 4; ++dt) {
                    short8 bf_ = *(const short8*)&VT[(dt * 16 + l16) * VST + ks * 32 + quad * 8];
                    O[dt] = MFMA16(af, bf_, O[dt]);
                }
            }
            for (int dt = 0; dt < 4; ++dt)
                for (int r = 0; r < 4; ++r) {
                    int m = qt * 16 + quad * 4 + r;
                    if (m < NPF) {
                        int tok = 1 + f * NPF + m;
                        qk[(basetok + tok) * QKCOLS + hc + dt * 16 + l16] =
                            f2bf(O[dt][r] * inv_sum[r]);
                    }
                }
        }
        __syncthreads();
    }
}

// ---------------------------------------------------------------------------
// CLS attention: one block per (b, h); CLS query attends to all 1569 keys.
// ---------------------------------------------------------------------------
__global__ __launch_bounds__(256) void cls_attn(short* __restrict__ qk,
                                                const short* __restrict__ vsrc) {
    __shared__ float qs[DHEAD];
    __shared__ float sexp[NTOK];
    __shared__ float red[8];
    __shared__ float partial[4][DHEAD];

    int h = blockIdx.x % NHEAD, b = blockIdx.x / NHEAD;
    const size_t basetok = (size_t)b * NTOK;
    const int hc = h * DHEAD;
    int tid = threadIdx.x;

    if (tid < DHEAD) qs[tid] = bf2f(qk[basetok * QKCOLS + hc + tid]) * 0.125f;
    __syncthreads();

    float lmax = -1e30f;
    for (int j = tid; j < NTOK; j += 256) {
        const short* krow = qk + (basetok + j) * QKCOLS + DIM + hc;
        float s = 0.f;
        for (int dd = 0; dd < DHEAD; ++dd) s += qs[dd] * bf2f(krow[dd]);
        sexp[j] = s;
        lmax = fmaxf(lmax, s);
    }
    for (int off = 1; off < 64; off <<= 1) lmax = fmaxf(lmax, __shfl_xor(lmax, off, 64));
    if ((tid & 63) == 0) red[tid >> 6] = lmax;
    __syncthreads();
    float mx = fmaxf(fmaxf(red[0], red[1]), fmaxf(red[2], red[3]));

    float lsum = 0.f;
    for (int j = tid; j < NTOK; j += 256) {
        float e = __expf(sexp[j] - mx);
        sexp[j] = e;
        lsum += e;
    }
    for (int off = 1; off < 64; off <<= 1) lsum += __shfl_xor(lsum, off, 64);
    if ((tid & 63) == 0) red[4 + (tid >> 6)] = lsum;
    __syncthreads();
    float sum = red[4] + red[5] + red[6] + red[7];

    int dd = tid & 63, strip = tid >> 6;
    float acc = 0.f;
    for (int j = strip; j < NTOK; j += 4)
        acc += sexp[j] * bf2f(vsrc[(basetok + j) * DIM + hc + dd]);
    partial[strip][dd] = acc;
    __syncthreads();

    if (tid < DHEAD) {
        float o = (partial[0][tid] + partial[1][tid] + partial[2][tid] + partial[3][tid]) / sum;
        qk[basetok * QKCOLS + hc + tid] = f2bf(o);
    }
}

// ---------------------------------------------------------------------------
extern "C" void kernel_launch(void* const* d_in, const int* in_sizes, int n_in,
                              void* d_out, int out_size, void* d_ws, size_t ws_size,
                              hipStream_t stream) {
    const float* x      = (const float*)d_in[0];   // (B, N, D) fp32
    const float* w_qkv  = (const float*)d_in[1];   // (D, 3D) fp32
    const float* w_proj = (const float*)d_in[2];   // (D, D) fp32
    const float* b_proj = (const float*)d_in[3];   // (D,) fp32
    float* out = (float*)d_out;                    // fp32 output (77.1 MB)

    // d_out doubles as scratch pre-proj: [xbf 38.56 MB | vbuf 38.56 MB]
    short* xbf  = (short*)d_out;
    short* vbuf = (short*)d_out + (size_t)MROWS * DIM;

    // ws: qk bf16 (MROWS x 1536) | wqkvT (2304x768) | wprojT (768x768) = ~82 MB
    const size_t QK_EL     = (size_t)MROWS * QKCOLS;
    const size_t WQKVT_EL  = (size_t)D3 * DIM;
    const size_t WPROJT_EL = (size_t)DIM * DIM;
    const size_t WS_NEEDED = (QK_EL + WQKVT_EL + WPROJT_EL) * sizeof(short);

    if (ws_size < WS_NEEDED) {
        zero_out_k<<<(out_size + 255) / 256, 256, 0, stream>>>(out, out_size);
        return;
    }

    short* qk     = (short*)d_ws;
    short* wqkvT  = qk + QK_EL;
    short* wprojT = wqkvT + WQKVT_EL;

    cvt_bf16_k<<<(MROWS * DIM / 8 + 255) / 256, 256, 0, stream>>>(x, xbf, MROWS * DIM / 8);
    transpose_cvt_k<<<dim3(D3 / 32, DIM / 32), 256, 0, stream>>>(w_qkv, wqkvT, DIM, D3);
    transpose_cvt_k<<<dim3(DIM / 32, DIM / 32), 256, 0, stream>>>(w_proj, wprojT, DIM, DIM);

    // qkv = xbf @ w_qkv ; cols 0..1535 (Q,K) -> qk, cols 1536.. (V) -> vbuf
    gemm_lds<false><<<dim3(D3 / 128, (MROWS + 127) / 128), 256, 0, stream>>>(
        xbf, DIM, wqkvT, nullptr, qk, QKCOLS, vbuf, DIM, QKCOLS, MROWS, DIM);

    frame_attn<<<BATCH * NHEAD * NFRAME, 256, 0, stream>>>(qk, vbuf);
    cls_attn<<<BATCH * NHEAD, 256, 0, stream>>>(qk, vbuf);

    // out = attnout @ w_proj + b_proj (attnout = qk's Q region, lda=1536; fp32 out)
    gemm_lds<true><<<dim3(DIM / 128, (MROWS + 127) / 128), 256, 0, stream>>>(
        qk, QKCOLS, wprojT, b_proj, out, DIM, nullptr, 0, 2 * DIM /*no split*/,
        MROWS, DIM);
}

// Round 5
// 611.128 us; speedup vs baseline: 2.4405x; 1.0262x over previous
//
#include <hip/hip_runtime.h>
#include <hip/hip_bf16.h>

// Problem constants (B=16, F=8, NP=196, D=768, H=12)
#define BATCH 16
#define NFRAME 8
#define NPF 196          // tokens per frame
#define DIM 768
#define NHEAD 12
#define DHEAD 64
#define NTOK 1569        // 1 + 8*196
#define MROWS (BATCH * NTOK)   // 25104
#define D3 (3 * DIM)           // 2304
#define QKCOLS 1536      // Q+K columns kept in ws (bf16)
#define NKEY 197         // CLS + frame keys
#define NKP 224          // padded keys (7*32)
#define VST 232          // LDS row stride (16B-aligned)
#define PST 232
#define NFBLK (BATCH * NHEAD * NFRAME)   // 1536 frame-attn blocks

typedef __attribute__((ext_vector_type(8))) short short8;
typedef __attribute__((ext_vector_type(4))) float floatx4;

#define MFMA16(A, B, C) __builtin_amdgcn_mfma_f32_16x16x32_bf16((A), (B), (C), 0, 0, 0)

__device__ __forceinline__ float bf2f(short s) {
    union { unsigned u; float f; } x;
    x.u = ((unsigned)(unsigned short)s) << 16;
    return x.f;
}
__device__ __forceinline__ short f2bf(float f) {
    union { float f; unsigned u; } x;
    x.f = f;
    unsigned r = x.u + 0x7fffu + ((x.u >> 16) & 1u);  // RNE
    return (short)(r >> 16);
}

// async global(bf16)->LDS, 16 bytes per lane
__device__ __forceinline__ void gld_lds16(const short* g, short* l) {
    __builtin_amdgcn_global_load_lds(
        (const __attribute__((address_space(1))) void*)g,
        (__attribute__((address_space(3))) void*)l, 16, 0, 0);
}

// ---------------------------------------------------------------------------
__global__ __launch_bounds__(256) void zero_out_k(float* __restrict__ out, int n) {
    int i = blockIdx.x * 256 + threadIdx.x;
    if (i < n) out[i] = 0.f;
}

// ---------------------------------------------------------------------------
// fp32 -> bf16 convert, 8 elements/thread
// ---------------------------------------------------------------------------
__global__ __launch_bounds__(256) void cvt_bf16_k(const float* __restrict__ in,
                                                  short* __restrict__ out, int n8) {
    int i = blockIdx.x * 256 + threadIdx.x;
    if (i < n8) {
        const float4* p = (const float4*)(in + (size_t)i * 8);
        float4 u0 = p[0], u1 = p[1];
        short8 t;
        t[0] = f2bf(u0.x); t[1] = f2bf(u0.y); t[2] = f2bf(u0.z); t[3] = f2bf(u0.w);
        t[4] = f2bf(u1.x); t[5] = f2bf(u1.y); t[6] = f2bf(u1.z); t[7] = f2bf(u1.w);
        *(short8*)(out + (size_t)i * 8) = t;
    }
}

// ---------------------------------------------------------------------------
// Weight transpose + fp32->bf16: in fp32 (R x C) -> out bf16 (C x R)
// ---------------------------------------------------------------------------
__global__ __launch_bounds__(256) void transpose_cvt_k(const float* __restrict__ in,
                                                       short* __restrict__ out,
                                                       int R, int C) {
    __shared__ float tile[32][33];
    int tx = threadIdx.x & 31, ty = threadIdx.x >> 5;
    int r0 = blockIdx.y * 32, c0 = blockIdx.x * 32;
    for (int i = 0; i < 4; ++i) {
        int r = ty + i * 8;
        tile[r][tx] = in[(size_t)(r0 + r) * C + c0 + tx];
    }
    __syncthreads();
    for (int i = 0; i < 4; ++i) {
        int c = ty + i * 8;
        out[(size_t)(c0 + c) * R + r0 + tx] = f2bf(tile[tx][c]);
    }
}

// ---------------------------------------------------------------------------
// LDS-tiled GEMM (m97 structure): C[M x Nc] = A[M x K] * BT[Nc x K]^T (+bias)
// 128x128 block tile, BK=32, 4 waves x (4x4 of 16x16x32 MFMA),
// global_load_lds width-16 staging, 2-barrier K-loop.
// Split store: global col < nsplit -> C0 else C1. grid = (Nc/128, ceil(M/128))
// ---------------------------------------------------------------------------
template <bool OF32>
__global__ __launch_bounds__(256) void gemm_lds(const short* __restrict__ A, int lda,
                                                const short* __restrict__ BT,
                                                const float* __restrict__ bias,
                                                void* __restrict__ C0v, int ldc0,
                                                void* __restrict__ C1v, int ldc1,
                                                int nsplit, int M, int K) {
    __shared__ __align__(16) short As[128 * 32];
    __shared__ __align__(16) short Bs[128 * 32];

    int tid = threadIdx.x;
    int lane = tid & 63, wid = tid >> 6;
    int l16 = lane & 15, quad = lane >> 4;
    int n0 = blockIdx.x * 128, m0 = blockIdx.y * 128;
    int wm = (wid & 1) * 64, wn = (wid >> 1) * 64;

    int id0 = tid, id1 = tid + 256;
    int ar0 = id0 >> 2, ak0 = (id0 & 3) * 8;
    int ar1 = id1 >> 2, ak1 = (id1 & 3) * 8;
    int ga0 = m0 + ar0; if (ga0 >= M) ga0 = M - 1;
    int ga1 = m0 + ar1; if (ga1 >= M) ga1 = M - 1;
    const short* Ap0 = A + (size_t)ga0 * lda + ak0;
    const short* Ap1 = A + (size_t)ga1 * lda + ak1;
    const short* Bp0 = BT + (size_t)(n0 + ar0) * K + ak0;
    const short* Bp1 = BT + (size_t)(n0 + ar1) * K + ak1;

    floatx4 acc[4][4];
    for (int mt = 0; mt < 4; ++mt)
        for (int nt = 0; nt < 4; ++nt)
            acc[mt][nt] = (floatx4){0.f, 0.f, 0.f, 0.f};

    for (int k0 = 0; k0 < K; k0 += 32) {
        if (k0) __syncthreads();
        gld_lds16(Ap0 + k0, &As[id0 * 8]);
        gld_lds16(Ap1 + k0, &As[id1 * 8]);
        gld_lds16(Bp0 + k0, &Bs[id0 * 8]);
        gld_lds16(Bp1 + k0, &Bs[id1 * 8]);
        __syncthreads();

        short8 a[4], b[4];
        for (int mt = 0; mt < 4; ++mt)
            a[mt] = *(const short8*)&As[(wm + mt * 16 + l16) * 32 + quad * 8];
        for (int nt = 0; nt < 4; ++nt)
            b[nt] = *(const short8*)&Bs[(wn + nt * 16 + l16) * 32 + quad * 8];
        for (int mt = 0; mt < 4; ++mt)
            for (int nt = 0; nt < 4; ++nt)
                acc[mt][nt] = MFMA16(a[mt], b[nt], acc[mt][nt]);
    }

    for (int mt = 0; mt < 4; ++mt)
        for (int nt = 0; nt < 4; ++nt) {
            int col0 = n0 + wn + nt * 16;
            void* dst;
            int ldc, cbase;
            if (col0 < nsplit) { dst = C0v; ldc = ldc0; cbase = col0; }
            else               { dst = C1v; ldc = ldc1; cbase = col0 - nsplit; }
            float bv = bias ? bias[col0 + l16] : 0.f;
            for (int r = 0; r < 4; ++r) {
                int row = m0 + wm + mt * 16 + quad * 4 + r;
                if (row < M) {
                    float v = acc[mt][nt][r] + bv;
                    if (OF32)
                        ((float*)dst)[(size_t)row * ldc + cbase + l16] = v;
                    else
                        ((short*)dst)[(size_t)row * ldc + cbase + l16] = f2bf(v);
                }
            }
        }
}

// ---------------------------------------------------------------------------
// Merged attention kernel.
// Blocks 0..1535: frame attention, one block (4 independent waves) per (b,h,f).
//   After the single V-staging barrier, waves run barrier-free: P is per-wave,
//   VT is read-only. Q read before O overwrites the same Q slots.
// Blocks 1536..1727: CLS attention, one block per (b,h).
// ---------------------------------------------------------------------------
struct FrameLds {
    short VT[DHEAD * VST];      // 29696 B
    short P[4][16 * PST];       // 29696 B
};
struct ClsLds {
    float qs[DHEAD];
    float sexp[NTOK];
    float red[8];
    float partial[4][DHEAD];
};
union AttnLds {
    FrameLds fa;
    ClsLds ca;
};

__global__ __launch_bounds__(256) void attn_k(short* __restrict__ qk,
                                              const short* __restrict__ vsrc) {
    __shared__ __align__(16) AttnLds u;

    if (blockIdx.x < NFBLK) {
        // ---------------- frame attention ----------------
        int blk = blockIdx.x;
        int f = blk & 7;
        int h = (blk >> 3) % NHEAD;
        int b = blk / (NHEAD * NFRAME);
        int lane = threadIdx.x & 63, wid = threadIdx.x >> 6;
        int l16 = lane & 15, quad = lane >> 4;
        const size_t basetok = (size_t)b * NTOK;
        const int hc = h * DHEAD;
        short* VT = u.fa.VT;
        short* Pw = u.fa.P[wid];

        for (int e = threadIdx.x; e < NKP * DHEAD; e += 256) {
            int j = e >> 6, dd = e & 63;
            short v = 0;
            if (j < NKEY) {
                int tok = (j == 0) ? 0 : (f * NPF + j);
                v = vsrc[(basetok + tok) * DIM + hc + dd];
            }
            VT[dd * VST + j] = v;
        }
        __syncthreads();   // the only block-wide barrier

        const float scale = 0.125f;  // d^-0.5, d=64

        for (int qt = wid; qt < 13; qt += 4) {
            floatx4 S[14];
            for (int nt = 0; nt < 14; ++nt) S[nt] = (floatx4){0.f, 0.f, 0.f, 0.f};

            int qm = qt * 16 + l16;
            if (qm > 195) qm = 195;       // clamp pad rows (results discarded)
            int qtok = 1 + f * NPF + qm;
            const short* qrow = qk + (basetok + qtok) * QKCOLS + hc;
            short8 afrag[2];
            afrag[0] = *(const short8*)(qrow + quad * 8);
            afrag[1] = *(const short8*)(qrow + 32 + quad * 8);

            for (int nt = 0; nt < 14; ++nt) {
                int key = nt * 16 + l16;
                int ktok = (key == 0) ? 0 : ((key <= 196) ? (f * NPF + key) : 0);
                const short* krow = qk + (basetok + ktok) * QKCOLS + DIM + hc;
                short8 b0 = *(const short8*)(krow + quad * 8);
                short8 b1 = *(const short8*)(krow + 32 + quad * 8);
                S[nt] = MFMA16(afrag[0], b0, S[nt]);
                S[nt] = MFMA16(afrag[1], b1, S[nt]);
            }

            for (int nt = 0; nt < 14; ++nt) {
                int key = nt * 16 + l16;
                float mask = (key < NKEY) ? 0.f : -1e30f;
                for (int r = 0; r < 4; ++r) S[nt][r] = S[nt][r] * scale + mask;
            }

            float inv_sum[4];
            for (int r = 0; r < 4; ++r) {
                float m = -1e30f;
                for (int nt = 0; nt < 14; ++nt) m = fmaxf(m, S[nt][r]);
                for (int off = 1; off < 16; off <<= 1) m = fmaxf(m, __shfl_xor(m, off, 64));
                float s = 0.f;
                for (int nt = 0; nt < 14; ++nt) {
                    float e = __expf(S[nt][r] - m);
                    S[nt][r] = e;
                    s += e;
                }
                for (int off = 1; off < 16; off <<= 1) s += __shfl_xor(s, off, 64);
                inv_sum[r] = 1.0f / s;
            }

            for (int nt = 0; nt < 14; ++nt)
                for (int r = 0; r < 4; ++r)
                    Pw[(quad * 4 + r) * PST + nt * 16 + l16] = f2bf(S[nt][r]);
            // intra-wave LDS write->read ordering: compiler-inserted lgkmcnt

            floatx4 O[4];
            for (int dt = 0; dt < 4; ++dt) O[dt] = (floatx4){0.f, 0.f, 0.f, 0.f};
            for (int ks = 0; ks < 7; ++ks) {
                short8 af = *(const short8*)&Pw[l16 * PST + ks * 32 + quad * 8];
                for (int dt = 0; dt < 4; ++dt) {
                    short8 bf_ = *(const short8*)&VT[(dt * 16 + l16) * VST + ks * 32 + quad * 8];
                    O[dt] = MFMA16(af, bf_, O[dt]);
                }
            }
            for (int dt = 0; dt < 4; ++dt)
                for (int r = 0; r < 4; ++r) {
                    int m = qt * 16 + quad * 4 + r;
                    if (m < NPF) {
                        int tok = 1 + f * NPF + m;
                        qk[(basetok + tok) * QKCOLS + hc + dt * 16 + l16] =
                            f2bf(O[dt][r] * inv_sum[r]);
                    }
                }
        }
    } else {
        // ---------------- CLS attention ----------------
        int cblk = blockIdx.x - NFBLK;
        int h = cblk % NHEAD, b = cblk / NHEAD;
        const size_t basetok = (size_t)b * NTOK;
        const int hc = h * DHEAD;
        int tid = threadIdx.x;
        ClsLds& ca = u.ca;

        if (tid < DHEAD) ca.qs[tid] = bf2f(qk[basetok * QKCOLS + hc + tid]) * 0.125f;
        __syncthreads();

        float lmax = -1e30f;
        for (int j = tid; j < NTOK; j += 256) {
            const short* krow = qk + (basetok + j) * QKCOLS + DIM + hc;
            float s = 0.f;
            for (int dd = 0; dd < DHEAD; ++dd) s += ca.qs[dd] * bf2f(krow[dd]);
            ca.sexp[j] = s;
            lmax = fmaxf(lmax, s);
        }
        for (int off = 1; off < 64; off <<= 1) lmax = fmaxf(lmax, __shfl_xor(lmax, off, 64));
        if ((tid & 63) == 0) ca.red[tid >> 6] = lmax;
        __syncthreads();
        float mx = fmaxf(fmaxf(ca.red[0], ca.red[1]), fmaxf(ca.red[2], ca.red[3]));

        float lsum = 0.f;
        for (int j = tid; j < NTOK; j += 256) {
            float e = __expf(ca.sexp[j] - mx);
            ca.sexp[j] = e;
            lsum += e;
        }
        for (int off = 1; off < 64; off <<= 1) lsum += __shfl_xor(lsum, off, 64);
        if ((tid & 63) == 0) ca.red[4 + (tid >> 6)] = lsum;
        __syncthreads();
        float sum = ca.red[4] + ca.red[5] + ca.red[6] + ca.red[7];

        int dd = tid & 63, strip = tid >> 6;
        float acc = 0.f;
        for (int j = strip; j < NTOK; j += 4)
            acc += ca.sexp[j] * bf2f(vsrc[(basetok + j) * DIM + hc + dd]);
        ca.partial[strip][dd] = acc;
        __syncthreads();

        if (tid < DHEAD) {
            float o = (ca.partial[0][tid] + ca.partial[1][tid] +
                       ca.partial[2][tid] + ca.partial[3][tid]) / sum;
            qk[basetok * QKCOLS + hc + tid] = f2bf(o);
        }
    }
}

// ---------------------------------------------------------------------------
extern "C" void kernel_launch(void* const* d_in, const int* in_sizes, int n_in,
                              void* d_out, int out_size, void* d_ws, size_t ws_size,
                              hipStream_t stream) {
    const float* x      = (const float*)d_in[0];   // (B, N, D) fp32
    const float* w_qkv  = (const float*)d_in[1];   // (D, 3D) fp32
    const float* w_proj = (const float*)d_in[2];   // (D, D) fp32
    const float* b_proj = (const float*)d_in[3];   // (D,) fp32
    float* out = (float*)d_out;                    // fp32 output (77.1 MB)

    // d_out doubles as scratch pre-proj: [xbf 38.56 MB | vbuf 38.56 MB]
    short* xbf  = (short*)d_out;
    short* vbuf = (short*)d_out + (size_t)MROWS * DIM;

    // ws: qk bf16 (MROWS x 1536) | wqkvT (2304x768) | wprojT (768x768) = ~82 MB
    const size_t QK_EL     = (size_t)MROWS * QKCOLS;
    const size_t WQKVT_EL  = (size_t)D3 * DIM;
    const size_t WPROJT_EL = (size_t)DIM * DIM;
    const size_t WS_NEEDED = (QK_EL + WQKVT_EL + WPROJT_EL) * sizeof(short);

    if (ws_size < WS_NEEDED) {
        zero_out_k<<<(out_size + 255) / 256, 256, 0, stream>>>(out, out_size);
        return;
    }

    short* qk     = (short*)d_ws;
    short* wqkvT  = qk + QK_EL;
    short* wprojT = wqkvT + WQKVT_EL;

    cvt_bf16_k<<<(MROWS * DIM / 8 + 255) / 256, 256, 0, stream>>>(x, xbf, MROWS * DIM / 8);
    transpose_cvt_k<<<dim3(D3 / 32, DIM / 32), 256, 0, stream>>>(w_qkv, wqkvT, DIM, D3);
    transpose_cvt_k<<<dim3(DIM / 32, DIM / 32), 256, 0, stream>>>(w_proj, wprojT, DIM, DIM);

    // qkv = xbf @ w_qkv ; cols 0..1535 (Q,K) -> qk, cols 1536.. (V) -> vbuf
    gemm_lds<false><<<dim3(D3 / 128, (MROWS + 127) / 128), 256, 0, stream>>>(
        xbf, DIM, wqkvT, nullptr, qk, QKCOLS, vbuf, DIM, QKCOLS, MROWS, DIM);

    attn_k<<<NFBLK + BATCH * NHEAD, 256, 0, stream>>>(qk, vbuf);

    // out = attnout @ w_proj + b_proj (attnout = qk's Q region, lda=1536; fp32 out)
    gemm_lds<true><<<dim3(DIM / 128, (MROWS + 127) / 128), 256, 0, stream>>>(
        qk, QKCOLS, wprojT, b_proj, out, DIM, nullptr, 0, 2 * DIM /*no split*/,
        MROWS, DIM);
}